// Round 15
// baseline (457.587 us; speedup 1.0000x reference)
//
#include <hip/hip_runtime.h>
#include <math.h>

typedef unsigned long long u64;
typedef unsigned int u32;
typedef _Float16 h8v __attribute__((ext_vector_type(8)));  // 8 fp16 (4 VGPRs)
typedef float    f4v __attribute__((ext_vector_type(4)));  // MFMA acc
typedef float    f2v __attribute__((ext_vector_type(2)));  // v_pk_*_f32 pair

#define MFMA16(a,b,c) __builtin_amdgcn_mfma_f32_16x16x32_f16(a, b, c, 0, 0, 0)

#define B_ 4
#define N_ 8192
#define K_ 16
#define W0_ 64
#define W1_ 128
#define W2_ 256
#define X0_ 96   // padded K-dim layer-1 inputs (64 feat + 3 coord + 29 zero)
#define X1_ 160  // padded K-dim layer-2 inputs (128 feat + 3 coord + 29 zero)

// ---------------- merged prep: points + weight conversions + part zeroing ----------------
// blocks [0, 8192): 4 points each -> coords4, fx0, fx1 tail
// blocks [8192, 8320): wconv layer1;  [8320, 8576): wconv layer2
// blocks [8576, 8832): head1 transpose;  block 8832: zero part (for fused gmax atomics)
__global__ __launch_bounds__(256) void prep_kernel(
    const float* __restrict__ x,
    const float* __restrict__ stem_w, const float* __restrict__ stem_b,
    const float* __restrict__ hmix_a, const float* __restrict__ hmix_b,
    const float* __restrict__ hmix_c,
    float* __restrict__ coords4, _Float16* __restrict__ fx0,
    _Float16* __restrict__ fx1,
    const float* __restrict__ b1_w, const float* __restrict__ b2_w,
    const float* __restrict__ h1w,
    _Float16* __restrict__ w1m, _Float16* __restrict__ w1d,
    _Float16* __restrict__ w2m, _Float16* __restrict__ w2d,
    _Float16* __restrict__ h1wT, float* __restrict__ part) {
  const int bi = blockIdx.x;
  const int tid = threadIdx.x;
  const int PB = (B_*N_)/4;          // 8192
  if (bi < PB) {
    const int p = bi * 4 + (tid >> 6);
    const int o = tid & 63;
    const float x0 = x[p*4+0], x1 = x[p*4+1], x2 = x[p*4+2], x3 = x[p*4+3];
    const float z = hmix_a[0]*x2 + hmix_b[0]*x3 + hmix_c[0];
    float acc = stem_b[o] + x0*stem_w[0*W0_+o] + x1*stem_w[1*W0_+o]
              + x2*stem_w[2*W0_+o] + x3*stem_w[3*W0_+o];
    fx0[p*X0_+o] = (_Float16)fmaxf(acc, 0.f);
    if (o < 32) {   // tail: 3 coords + 29 zeros (both layers' inputs)
      const float tv = (o==0) ? x0 : (o==1) ? x1 : (o==2) ? z : 0.f;
      fx0[p*X0_+W0_+o] = (_Float16)tv;
      fx1[(size_t)p*X1_+W1_+o] = (_Float16)tv;
    }
    if (o == 0) {
      const float xx = x0*x0 + x1*x1 + z*z;
      ((float4*)coords4)[p] = make_float4(x0, x1, z, xx);
    }
  } else if (bi < PB + W1_) {        // wconv layer1
    const int o = bi - PB, c = tid;
    if (c < X0_) {
      float mv = 0.f, dv = 0.f;
      if (c < W0_)        { const float wm = b1_w[(W0_+c)*W1_+o]; mv = wm; dv = b1_w[c*W1_+o] - wm; }
      else if (c < W0_+3) { const float wp = b1_w[(2*W0_+(c-W0_))*W1_+o]; mv = wp; dv = -wp; }
      w1m[o*X0_+c] = (_Float16)mv;
      w1d[o*X0_+c] = (_Float16)dv;
    }
  } else if (bi < PB + W1_ + W2_) {  // wconv layer2
    const int o = bi - PB - W1_, c = tid;
    if (c < X1_) {
      float mv = 0.f, dv = 0.f;
      if (c < W1_)        { const float wm = b2_w[(W1_+c)*W2_+o]; mv = wm; dv = b2_w[c*W2_+o] - wm; }
      else if (c < W1_+3) { const float wp = b2_w[(2*W1_+(c-W1_))*W2_+o]; mv = wp; dv = -wp; }
      w2m[o*X1_+c] = (_Float16)mv;
      w2d[o*X1_+c] = (_Float16)dv;
    }
  } else if (bi < PB + W1_ + 2*W2_) { // head1 transpose
    const int o = bi - PB - W1_ - W2_;
    for (int c = tid; c < 512; c += 256)
      h1wT[(size_t)o*512 + c] = (_Float16)h1w[(size_t)c*256 + o];
  } else {                            // zero part (B_*W2_ = 1024 floats)
    ((float4*)part)[tid] = make_float4(0.f, 0.f, 0.f, 0.f);
  }
}

// ---------------- knn: 4 waves x 8 points, packed-f32 distances, threshold pre-pass ----------------
// Selection exact (r9 bound proof). r15: 8 points/wave amortizes per-iter fixed
// costs (addressing, cj load, loop) over 2x distance work.
#define DPP_SHR1(v) __builtin_amdgcn_update_dpp(0, (v), 0x138, 0xF, 0xF, false)

#define DPP_MIN(v, ctrl)                                                        \
  { const int _t = __builtin_amdgcn_update_dpp(__float_as_int(v),               \
      __float_as_int(v), ctrl, 0xF, 0xF, false);                                \
    v = fminf(v, __int_as_float(_t)); }

__device__ __forceinline__ float sixteenth_of_minima(float v) {
  float th = 0.f;
#pragma unroll
  for (int r = 0; r < 16; ++r) {
    float w = v;
    DPP_MIN(w, 0x111); DPP_MIN(w, 0x112); DPP_MIN(w, 0x114); DPP_MIN(w, 0x118);
    DPP_MIN(w, 0x142); DPP_MIN(w, 0x143);   // row_bcast15 / row_bcast31
    const float mv = __int_as_float(
        __builtin_amdgcn_readlane(__float_as_int(w), 63));
    th = mv;
    v = (v == mv) ? INFINITY : v;
  }
  return th;
}

#define KNN_EVT(d, dk, ik)                                                      \
  {                                                                             \
    const int s = (int)__ffsll((unsigned long long)m) - 1;  m &= m - 1;         \
    const float dc = __int_as_float(__builtin_amdgcn_readlane(                  \
                       __float_as_int(d), s));                                  \
    const bool cnd = dc < dk;                                                   \
    const u64 cm = __ballot(cnd) << 1;                                          \
    const float pd = __int_as_float(DPP_SHR1(__float_as_int(dk)));              \
    const int   pi = DPP_SHR1(ik);                                              \
    const bool pc = (cm >> lane) & 1;                                           \
    dk = cnd ? (pc ? pd : dc) : dk;                                             \
    ik = cnd ? (pc ? pi : (jbase + s)) : ik;                                    \
  }

#define KNN_CHUNK(d, dk, ik, T, Th)                                             \
  { u64 m = __ballot(d <= T);                                                   \
    if (m) {                                                                    \
      do { KNN_EVT(d, dk, ik) } while (m);                                      \
      T = fminf(Th, __int_as_float(__builtin_amdgcn_readlane(                   \
            __float_as_int(dk), 15)));                                          \
    }                                                                           \
  }

// packed distances for 8 points (4 pairs), clamped
#define KNN_DIST8                                                               \
  const f2v cjx = {cj.x, cj.x}, cjy = {cj.y, cj.y},                             \
            cjz = {cj.z, cj.z}, cjw = {cj.w, cj.w};                             \
  f2v dd[4];                                                                    \
  _Pragma("unroll")                                                             \
  for (int q = 0; q < 4; ++q) {                                                 \
    f2v t = cx[q] * cjx;                                                        \
    t = __builtin_elementwise_fma(cy[q], cjy, t);                               \
    t = __builtin_elementwise_fma(cz[q], cjz, t);                               \
    const f2v dr = __builtin_elementwise_fma(t, m2, cw[q] + cjw);               \
    dd[q] = __builtin_elementwise_max(dr, (f2v){0.f, 0.f});                     \
  }

__global__ __launch_bounds__(256) void knn_kernel(
    const float* __restrict__ coords4, int* __restrict__ knn_idx) {
  const int tid = threadIdx.x;
  const int wid = tid >> 6;
  const int lane = tid & 63;
  const int p0 = blockIdx.x * 32 + wid * 8;   // block of 32 never straddles batch
  const int b = p0 >> 13;
  const float4* cb = ((const float4*)coords4) + (b << 13);
  const f2v m2 = {-2.f, -2.f};

  f2v cx[4], cy[4], cz[4], cw[4];
#pragma unroll
  for (int q = 0; q < 4; ++q) {
    const float4 ca = ((const float4*)coords4)[p0 + 2*q];
    const float4 cbq = ((const float4*)coords4)[p0 + 2*q + 1];
    cx[q] = (f2v){ca.x, cbq.x}; cy[q] = (f2v){ca.y, cbq.y};
    cz[q] = (f2v){ca.z, cbq.z}; cw[q] = (f2v){ca.w, cbq.w};
  }

  // ---- pass A: per-lane minima over the first half (straight-line, no events)
  float lm[8];
#pragma unroll
  for (int i = 0; i < 8; ++i) lm[i] = INFINITY;
  for (int it = 0; it < 64; ++it) {
    const float4 cj = cb[it*64 + lane];
    KNN_DIST8
#pragma unroll
    for (int i = 0; i < 8; ++i) lm[i] = fminf(lm[i], dd[i>>1][i&1]);
  }

  float Th[8], T[8], dk[8];
  int ik[8];
#pragma unroll
  for (int i = 0; i < 8; ++i) {
    Th[i] = sixteenth_of_minima(lm[i]);
    T[i] = Th[i];
    dk[i] = INFINITY;
    ik[i] = 0;
  }

  // ---- main pass: all candidates, events only below the tight bound
  for (int it = 0; it < N_/64; ++it) {
    const int jbase = it*64;
    const float4 cj = cb[jbase + lane];
    KNN_DIST8
    KNN_CHUNK(dd[0][0], dk[0], ik[0], T[0], Th[0]);
    KNN_CHUNK(dd[0][1], dk[1], ik[1], T[1], Th[1]);
    KNN_CHUNK(dd[1][0], dk[2], ik[2], T[2], Th[2]);
    KNN_CHUNK(dd[1][1], dk[3], ik[3], T[3], Th[3]);
    KNN_CHUNK(dd[2][0], dk[4], ik[4], T[4], Th[4]);
    KNN_CHUNK(dd[2][1], dk[5], ik[5], T[5], Th[5]);
    KNN_CHUNK(dd[3][0], dk[6], ik[6], T[6], Th[6]);
    KNN_CHUNK(dd[3][1], dk[7], ik[7], T[7], Th[7]);
  }

  if (lane < K_) {
#pragma unroll
    for (int i = 0; i < 8; ++i)
      knn_idx[(size_t)(p0+i)*K_ + lane] = ik[i];
  }
}

// ---------------- MFMA local_agg: transposed layout + LDS dbuf + optional fused gmax ----------------
template<int KS, int NPASS, bool GMAX>
__global__ __launch_bounds__(256) void aggm_kernel(
    const _Float16* __restrict__ fx, const int* __restrict__ knn_idx,
    const _Float16* __restrict__ midT, const _Float16* __restrict__ difT,
    const float* __restrict__ bw,
    _Float16* __restrict__ fo, const int ostr, u32* __restrict__ part) {
  const int XD  = KS*32;
  const int XDP = XD + 8;               // +16B pad per row
  const int CH  = KS*4;                 // uint4 chunks per row
  const int p0 = blockIdx.x * 16;
  const int bb = (p0 >> 13) << 13;
  const int tid = threadIdx.x;
  const int w = tid >> 6, lane = tid & 63, col = lane & 15, quad = lane >> 4;
  const int koff = quad * 8;

  __shared__ int s_idx[256];            // [point m][k]
  __shared__ _Float16 sA[2][16*(KS*32+8)];

  s_idx[tid] = knn_idx[p0*K_ + tid];

  // ---- C part (k-independent): A = own 16 point rows, B = difT ----
  f4v cacc[NPASS][2];
  {
    h8v Ao[KS];
    const _Float16* ap = fx + (size_t)(p0+col)*XD + koff;
#pragma unroll
    for (int kk = 0; kk < KS; ++kk) Ao[kk] = *(const h8v*)(ap + kk*32);
#pragma unroll
    for (int ps = 0; ps < NPASS; ++ps) {
      const int o0 = ps*128 + w*32;
      const _Float16* b0 = difT + (size_t)(o0 + col)*XD + koff;
      const _Float16* b1 = difT + (size_t)(o0 + 16 + col)*XD + koff;
      f4v c0 = {0.f,0.f,0.f,0.f}, c1 = {0.f,0.f,0.f,0.f};
#pragma unroll
      for (int kk = 0; kk < KS; ++kk) {
        c0 = MFMA16(Ao[kk], *(const h8v*)(b0 + kk*32), c0);
        c1 = MFMA16(Ao[kk], *(const h8v*)(b1 + kk*32), c1);
      }
      cacc[ps][0] = c0; cacc[ps][1] = c1;
    }
  }

  // ---- B fragments for ALL passes in registers ----
  h8v Bf[NPASS][2][KS];
  float bias[NPASS][2];
#pragma unroll
  for (int ps = 0; ps < NPASS; ++ps) {
    const int o0 = ps*128 + w*32;
#pragma unroll
    for (int kk = 0; kk < KS; ++kk) {
      Bf[ps][0][kk] = *(const h8v*)(midT + (size_t)(o0 + col)*XD + kk*32 + koff);
      Bf[ps][1][kk] = *(const h8v*)(midT + (size_t)(o0 + 16 + col)*XD + kk*32 + koff);
    }
    bias[ps][0] = bw[o0 + col];
    bias[ps][1] = bw[o0 + 16 + col];
  }
  __syncthreads();   // s_idx ready

  // ---- stage k=0 ----
  for (int c = tid; c < 16*CH; c += 256) {
    const int r = c / CH, o = c - r*CH;
    *(uint4*)&sA[0][r*XDP + o*8] =
        *(const uint4*)(fx + (size_t)(bb + s_idx[r<<4])*XD + o*8);
  }
  __syncthreads();

  f4v M[NPASS][2];
#pragma unroll
  for (int ps = 0; ps < NPASS; ++ps) {
    M[ps][0] = (f4v){-INFINITY,-INFINITY,-INFINITY,-INFINITY};
    M[ps][1] = (f4v){-INFINITY,-INFINITY,-INFINITY,-INFINITY};
  }

  for (int k = 0; k < 16; ++k) {
    const int buf = k & 1;
    if (k < 15) {   // stage k+1 into the other buffer
      for (int c = tid; c < 16*CH; c += 256) {
        const int r = c / CH, o = c - r*CH;
        *(uint4*)&sA[buf^1][r*XDP + o*8] =
            *(const uint4*)(fx + (size_t)(bb + s_idx[(r<<4) + k + 1])*XD + o*8);
      }
    }
    h8v Ac[KS];
    const _Float16* ap = &sA[buf][col*XDP + koff];
#pragma unroll
    for (int kk = 0; kk < KS; ++kk) Ac[kk] = *(const h8v*)(ap + kk*32);
#pragma unroll
    for (int ps = 0; ps < NPASS; ++ps) {
      f4v d0 = {0.f,0.f,0.f,0.f}, d1 = {0.f,0.f,0.f,0.f};
#pragma unroll
      for (int kk = 0; kk < KS; ++kk) {
        d0 = MFMA16(Ac[kk], Bf[ps][0][kk], d0);
        d1 = MFMA16(Ac[kk], Bf[ps][1][kk], d1);
      }
#pragma unroll
      for (int e = 0; e < 4; ++e) {
        M[ps][0][e] = fmaxf(M[ps][0][e], d0[e]);
        M[ps][1][e] = fmaxf(M[ps][1][e], d1[e]);
      }
    }
    __syncthreads();   // staged data visible; readers done before overwrite
  }

  // ---- epilogue: out[p][o] = max(M + C + bias, 0); lane holds rows quad*4+reg ----
  const int prow = p0 + (quad << 2);
  const int bq = p0 >> 13;
#pragma unroll
  for (int ps = 0; ps < NPASS; ++ps) {
    const int o0 = ps*128 + w*32;
    const int oa = o0 + col, ob = oa + 16;
    float v0[4], v1[4];
#pragma unroll
    for (int reg = 0; reg < 4; ++reg) {
      v0[reg] = fmaxf(M[ps][0][reg] + cacc[ps][0][reg] + bias[ps][0], 0.f);
      v1[reg] = fmaxf(M[ps][1][reg] + cacc[ps][1][reg] + bias[ps][1], 0.f);
      fo[(size_t)(prow+reg)*ostr + oa] = (_Float16)v0[reg];
      fo[(size_t)(prow+reg)*ostr + ob] = (_Float16)v1[reg];
    }
    if (GMAX) {   // block-local max over 16 points, then one atomic per output
      float bm0 = fmaxf(fmaxf(v0[0], v0[1]), fmaxf(v0[2], v0[3]));
      float bm1 = fmaxf(fmaxf(v1[0], v1[1]), fmaxf(v1[2], v1[3]));
      bm0 = fmaxf(bm0, __shfl_xor(bm0, 16, 64));
      bm0 = fmaxf(bm0, __shfl_xor(bm0, 32, 64));
      bm1 = fmaxf(bm1, __shfl_xor(bm1, 16, 64));
      bm1 = fmaxf(bm1, __shfl_xor(bm1, 32, 64));
      if (quad == 0) {
        atomicMax(part + bq*W2_ + oa, __float_as_uint(bm0));
        atomicMax(part + bq*W2_ + ob, __float_as_uint(bm1));
      }
    }
  }
}

// ---------------- head: 32 points/block MFMA GEMM + fused glob FC + second layer ----------------
// r15: g computed in-block from part (bitwise identical to old gfc: same f32
// order, single fp16 round); g fragments live in s_gh and serve BOTH point
// groups (kk>=8 rows of A are identical) -> gfc dispatch eliminated.
__global__ __launch_bounds__(256) void headm_kernel(
    const _Float16* __restrict__ f2h, const float* __restrict__ part,
    const float* __restrict__ gw, const float* __restrict__ gb,
    const _Float16* __restrict__ h1wT, const float* __restrict__ h1b,
    const float* __restrict__ h2w, const float* __restrict__ h2b,
    const float* __restrict__ x,
    const float* __restrict__ thresh, const float* __restrict__ sharp,
    const float* __restrict__ scale,
    float* __restrict__ out) {
  const int p0 = blockIdx.x * 32;
  const int b = p0 >> 13;
  const int tid = threadIdx.x;
  const int w = tid >> 6, lane = tid & 63, col = lane & 15, quad = lane >> 4;

  __shared__ float    s_part[W2_];
  __shared__ _Float16 s_gh[W2_];
  __shared__ _Float16 sA[32*264];   // 32 points x 256 f2h features (pad 264)
  __shared__ float    sh[32*260];   // relu(h1) f32

  s_part[tid] = part[b*W2_ + tid];  // bits from atomicMax(u32) == float bits (>=0)
  for (int t = tid; t < 32*32; t += 256) {       // f2h part (16B chunks)
    const int r = t >> 5, cc = (t & 31) * 8;
    *(uint4*)&sA[r*264 + cc] = *(const uint4*)&f2h[(size_t)(p0+r)*W2_ + cc];
  }
  __syncthreads();

  {
    float gacc = gb[tid];
    for (int d = 0; d < W2_; ++d) gacc += s_part[d]*gw[d*W2_ + tid];
    s_gh[tid] = (_Float16)fmaxf(gacc, 0.f);
  }
  __syncthreads();

  f4v acc[2][4];
#pragma unroll
  for (int r = 0; r < 2; ++r)
#pragma unroll
    for (int t = 0; t < 4; ++t) acc[r][t] = (f4v){0.f,0.f,0.f,0.f};

#pragma unroll
  for (int kk = 0; kk < 16; ++kk) {
    h8v a0, a1;
    if (kk < 8) {
      a0 = *(const h8v*)&sA[col*264 + kk*32 + quad*8];
      a1 = *(const h8v*)&sA[(16+col)*264 + kk*32 + quad*8];
    } else {
      a0 = *(const h8v*)&s_gh[(kk-8)*32 + quad*8];
      a1 = a0;
    }
#pragma unroll
    for (int t = 0; t < 4; ++t) {
      const h8v bt = *(const h8v*)&h1wT[(size_t)(w*64 + t*16 + col)*512 + kk*32 + quad*8];
      acc[0][t] = MFMA16(a0, bt, acc[0][t]);
      acc[1][t] = MFMA16(a1, bt, acc[1][t]);
    }
  }
#pragma unroll
  for (int r = 0; r < 2; ++r)
#pragma unroll
    for (int t = 0; t < 4; ++t) {
      const int o = w*64 + t*16 + col;
      const float bv = h1b[o];
#pragma unroll
      for (int reg = 0; reg < 4; ++reg)
        sh[(r*16 + quad*4 + reg)*260 + o] = fmaxf(acc[r][t][reg] + bv, 0.f);
    }
  __syncthreads();

  if (tid < 96) {
    const int pp = tid / 3, c = tid % 3;
    float s = h2b[c];
    for (int d = 0; d < 256; ++d) s += sh[pp*260 + d] * h2w[d*3 + c];
    if (c == 0) {
      const float hag = x[(size_t)(p0+pp)*4 + 3];
      s += scale[0] / (1.f + expf(-sharp[0]*(thresh[0] - hag)));
    }
    out[(size_t)(p0+pp)*3 + c] = s;
  }
}

// ---------------- launch ----------------
extern "C" void kernel_launch(void* const* d_in, const int* in_sizes, int n_in,
                              void* d_out, int out_size, void* d_ws, size_t ws_size,
                              hipStream_t stream) {
  const float* x       = (const float*)d_in[0];
  const float* hmix_a  = (const float*)d_in[1];
  const float* hmix_b  = (const float*)d_in[2];
  const float* hmix_c  = (const float*)d_in[3];
  const float* stem_w  = (const float*)d_in[4];
  const float* stem_b  = (const float*)d_in[5];
  const float* b1_w    = (const float*)d_in[6];
  const float* b1_b    = (const float*)d_in[7];
  const float* b2_w    = (const float*)d_in[8];
  const float* b2_b    = (const float*)d_in[9];
  const float* glob_w  = (const float*)d_in[10];
  const float* glob_b  = (const float*)d_in[11];
  const float* head1_w = (const float*)d_in[12];
  const float* head1_b = (const float*)d_in[13];
  const float* head2_w = (const float*)d_in[14];
  const float* head2_b = (const float*)d_in[15];
  const float* thresh  = (const float*)d_in[16];
  const float* sharp   = (const float*)d_in[17];
  const float* scale   = (const float*)d_in[18];
  float* out = (float*)d_out;

  char* base = (char*)d_ws;
  float*     coords4 = (float*)    (base + 0);          // 512 KB
  int*       idxb    = (int*)      (base + 524288);     // 2 MB
  _Float16*  fx0     = (_Float16*) (base + 2621440);    // 6 MB   (32768*96*2)
  _Float16*  fx1     = (_Float16*) (base + 8912896);    // 10 MB  (32768*160*2)
  _Float16*  f2h     = (_Float16*) (base + 19398656);   // 16 MB  (32768*256*2)
  _Float16*  w1m     = (_Float16*) (base + 36175872);   // 24 KB  (128*96*2)
  _Float16*  w1d     = (_Float16*) (base + 36200448);   // 24 KB
  _Float16*  w2m     = (_Float16*) (base + 36225024);   // 80 KB  (256*160*2)
  _Float16*  w2d     = (_Float16*) (base + 36306944);   // 80 KB
  _Float16*  h1wT    = (_Float16*) (base + 36388864);   // 256 KB (256*512*2)
  float*     part    = (float*)    (base + 36651008);   // 4 KB (4*256 f32, fused max)
  const int NP = B_ * N_;   // 32768 points

  prep_kernel<<<NP/4 + W1_ + 2*W2_ + 1, 256, 0, stream>>>(
      x, stem_w, stem_b, hmix_a, hmix_b, hmix_c, coords4, fx0, fx1,
      b1_w, b2_w, head1_w, w1m, w1d, w2m, w2d, h1wT, part);
  knn_kernel<<<NP/32, 256, 0, stream>>>(coords4, idxb);
  aggm_kernel<3, 1, false><<<NP/16, 256, 0, stream>>>(
      fx0, idxb, w1m, w1d, b1_b, fx1, X1_, (u32*)0);
  aggm_kernel<5, 2, true><<<NP/16, 256, 0, stream>>>(
      fx1, idxb, w2m, w2d, b2_b, f2h, W2_, (u32*)part);
  headm_kernel<<<NP/32, 256, 0, stream>>>(f2h, part, glob_w, glob_b,
                                          h1wT, head1_b, head2_w, head2_b,
                                          x, thresh, sharp, scale, out);
}

// Round 16
// 413.035 us; speedup vs baseline: 1.1079x; 1.1079x over previous
//
#include <hip/hip_runtime.h>
#include <math.h>

typedef unsigned long long u64;
typedef unsigned int u32;
typedef _Float16 h8v __attribute__((ext_vector_type(8)));  // 8 fp16 (4 VGPRs)
typedef float    f4v __attribute__((ext_vector_type(4)));  // MFMA acc
typedef float    f2v __attribute__((ext_vector_type(2)));  // v_pk_*_f32 pair

#define MFMA16(a,b,c) __builtin_amdgcn_mfma_f32_16x16x32_f16(a, b, c, 0, 0, 0)

#define B_ 4
#define N_ 8192
#define K_ 16
#define W0_ 64
#define W1_ 128
#define W2_ 256
#define X0_ 96   // padded K-dim layer-1 inputs (64 feat + 3 coord + 29 zero)
#define X1_ 160  // padded K-dim layer-2 inputs (128 feat + 3 coord + 29 zero)

// ---------------- merged prep: points + weight conversions + part zeroing ----------------
__global__ __launch_bounds__(256) void prep_kernel(
    const float* __restrict__ x,
    const float* __restrict__ stem_w, const float* __restrict__ stem_b,
    const float* __restrict__ hmix_a, const float* __restrict__ hmix_b,
    const float* __restrict__ hmix_c,
    float* __restrict__ coords4, _Float16* __restrict__ fx0,
    _Float16* __restrict__ fx1,
    const float* __restrict__ b1_w, const float* __restrict__ b2_w,
    const float* __restrict__ h1w,
    _Float16* __restrict__ w1m, _Float16* __restrict__ w1d,
    _Float16* __restrict__ w2m, _Float16* __restrict__ w2d,
    _Float16* __restrict__ h1wT, float* __restrict__ part) {
  const int bi = blockIdx.x;
  const int tid = threadIdx.x;
  const int PB = (B_*N_)/4;          // 8192
  if (bi < PB) {
    const int p = bi * 4 + (tid >> 6);
    const int o = tid & 63;
    const float x0 = x[p*4+0], x1 = x[p*4+1], x2 = x[p*4+2], x3 = x[p*4+3];
    const float z = hmix_a[0]*x2 + hmix_b[0]*x3 + hmix_c[0];
    float acc = stem_b[o] + x0*stem_w[0*W0_+o] + x1*stem_w[1*W0_+o]
              + x2*stem_w[2*W0_+o] + x3*stem_w[3*W0_+o];
    fx0[p*X0_+o] = (_Float16)fmaxf(acc, 0.f);
    if (o < 32) {   // tail: 3 coords + 29 zeros (both layers' inputs)
      const float tv = (o==0) ? x0 : (o==1) ? x1 : (o==2) ? z : 0.f;
      fx0[p*X0_+W0_+o] = (_Float16)tv;
      fx1[(size_t)p*X1_+W1_+o] = (_Float16)tv;
    }
    if (o == 0) {
      const float xx = x0*x0 + x1*x1 + z*z;
      ((float4*)coords4)[p] = make_float4(x0, x1, z, xx);
    }
  } else if (bi < PB + W1_) {        // wconv layer1
    const int o = bi - PB, c = tid;
    if (c < X0_) {
      float mv = 0.f, dv = 0.f;
      if (c < W0_)        { const float wm = b1_w[(W0_+c)*W1_+o]; mv = wm; dv = b1_w[c*W1_+o] - wm; }
      else if (c < W0_+3) { const float wp = b1_w[(2*W0_+(c-W0_))*W1_+o]; mv = wp; dv = -wp; }
      w1m[o*X0_+c] = (_Float16)mv;
      w1d[o*X0_+c] = (_Float16)dv;
    }
  } else if (bi < PB + W1_ + W2_) {  // wconv layer2
    const int o = bi - PB - W1_, c = tid;
    if (c < X1_) {
      float mv = 0.f, dv = 0.f;
      if (c < W1_)        { const float wm = b2_w[(W1_+c)*W2_+o]; mv = wm; dv = b2_w[c*W2_+o] - wm; }
      else if (c < W1_+3) { const float wp = b2_w[(2*W1_+(c-W1_))*W2_+o]; mv = wp; dv = -wp; }
      w2m[o*X1_+c] = (_Float16)mv;
      w2d[o*X1_+c] = (_Float16)dv;
    }
  } else if (bi < PB + W1_ + 2*W2_) { // head1 transpose
    const int o = bi - PB - W1_ - W2_;
    for (int c = tid; c < 512; c += 256)
      h1wT[(size_t)o*512 + c] = (_Float16)h1w[(size_t)c*256 + o];
  } else {                            // zero part (B_*W2_ = 1024 floats)
    ((float4*)part)[tid] = make_float4(0.f, 0.f, 0.f, 0.f);
  }
}

// ---------------- knn: 4 waves x 4 points, packed-f32 distances, threshold pre-pass ----------------
// Selection exact (r9 bound proof; T-hat from ANY candidate subset is a valid
// upper bound on d16 — pass A samples a quarter: slightly looser bound,
// fewer pass-A instructions). 4-pt/wave = r14 config (8-pt refuted in r15).
#define DPP_SHR1(v) __builtin_amdgcn_update_dpp(0, (v), 0x138, 0xF, 0xF, false)

#define DPP_MIN(v, ctrl)                                                        \
  { const int _t = __builtin_amdgcn_update_dpp(__float_as_int(v),               \
      __float_as_int(v), ctrl, 0xF, 0xF, false);                                \
    v = fminf(v, __int_as_float(_t)); }

__device__ __forceinline__ float sixteenth_of_minima(float v) {
  float th = 0.f;
#pragma unroll
  for (int r = 0; r < 16; ++r) {
    float w = v;
    DPP_MIN(w, 0x111); DPP_MIN(w, 0x112); DPP_MIN(w, 0x114); DPP_MIN(w, 0x118);
    DPP_MIN(w, 0x142); DPP_MIN(w, 0x143);   // row_bcast15 / row_bcast31
    const float mv = __int_as_float(
        __builtin_amdgcn_readlane(__float_as_int(w), 63));
    th = mv;
    v = (v == mv) ? INFINITY : v;
  }
  return th;
}

#define KNN_EVT(d, dk, ik)                                                      \
  {                                                                             \
    const int s = (int)__ffsll((unsigned long long)m) - 1;  m &= m - 1;         \
    const float dc = __int_as_float(__builtin_amdgcn_readlane(                  \
                       __float_as_int(d), s));                                  \
    const bool cnd = dc < dk;                                                   \
    const u64 cm = __ballot(cnd) << 1;                                          \
    const float pd = __int_as_float(DPP_SHR1(__float_as_int(dk)));              \
    const int   pi = DPP_SHR1(ik);                                              \
    const bool pc = (cm >> lane) & 1;                                           \
    dk = cnd ? (pc ? pd : dc) : dk;                                             \
    ik = cnd ? (pc ? pi : (jbase + s)) : ik;                                    \
  }

#define KNN_CHUNK(d, dk, ik, T, Th)                                             \
  { u64 m = __ballot(d <= T);                                                   \
    if (m) {                                                                    \
      do { KNN_EVT(d, dk, ik) } while (m);                                      \
      T = fminf(Th, __int_as_float(__builtin_amdgcn_readlane(                   \
            __float_as_int(dk), 15)));                                          \
    }                                                                           \
  }

#define KNN_DIST2(dA, dB)                                                       \
  const f2v cjx = {cj.x, cj.x}, cjy = {cj.y, cj.y},                             \
            cjz = {cj.z, cj.z}, cjw = {cj.w, cj.w};                             \
  f2v tA = cAx * cjx;                                                           \
  tA = __builtin_elementwise_fma(cAy, cjy, tA);                                 \
  tA = __builtin_elementwise_fma(cAz, cjz, tA);                                 \
  const f2v dA = __builtin_elementwise_fma(tA, m2, cAw + cjw);                  \
  f2v tB = cBx * cjx;                                                           \
  tB = __builtin_elementwise_fma(cBy, cjy, tB);                                 \
  tB = __builtin_elementwise_fma(cBz, cjz, tB);                                 \
  const f2v dB = __builtin_elementwise_fma(tB, m2, cBw + cjw);

__global__ __launch_bounds__(256, 8) void knn_kernel(
    const float* __restrict__ coords4, int* __restrict__ knn_idx) {
  const int tid = threadIdx.x;
  const int wid = tid >> 6;
  const int lane = tid & 63;
  const int p0 = blockIdx.x * 16 + wid * 4;   // block of 16 never straddles batch
  const int b = p0 >> 13;
  const float4* cb = ((const float4*)coords4) + (b << 13);
  const float4 c0 = ((const float4*)coords4)[p0+0];
  const float4 c1 = ((const float4*)coords4)[p0+1];
  const float4 c2 = ((const float4*)coords4)[p0+2];
  const float4 c3 = ((const float4*)coords4)[p0+3];
  const f2v m2 = {-2.f, -2.f};
  const f2v cAx = {c0.x, c1.x}, cAy = {c0.y, c1.y}, cAz = {c0.z, c1.z}, cAw = {c0.w, c1.w};
  const f2v cBx = {c2.x, c3.x}, cBy = {c2.y, c3.y}, cBz = {c2.z, c3.z}, cBw = {c2.w, c3.w};

  // ---- pass A: per-lane minima over a quarter sample (straight-line, no events)
  float lm0 = INFINITY, lm1 = INFINITY, lm2 = INFINITY, lm3 = INFINITY;
  for (int it = 0; it < 32; ++it) {
    const float4 cj = cb[it*64 + lane];
    KNN_DIST2(dA, dB)
    lm0 = fminf(lm0, fmaxf(dA[0], 0.f));
    lm1 = fminf(lm1, fmaxf(dA[1], 0.f));
    lm2 = fminf(lm2, fmaxf(dB[0], 0.f));
    lm3 = fminf(lm3, fmaxf(dB[1], 0.f));
  }
  const float Th0 = sixteenth_of_minima(lm0);
  const float Th1 = sixteenth_of_minima(lm1);
  const float Th2 = sixteenth_of_minima(lm2);
  const float Th3 = sixteenth_of_minima(lm3);

  float dk0 = INFINITY, dk1 = INFINITY, dk2 = INFINITY, dk3 = INFINITY;
  int   ik0 = 0, ik1 = 0, ik2 = 0, ik3 = 0;
  float T0 = Th0, T1 = Th1, T2 = Th2, T3 = Th3;

  // ---- main pass: all candidates, events only below the bound
  for (int it = 0; it < N_/64; ++it) {
    const int jbase = it*64;
    const float4 cj = cb[jbase + lane];
    KNN_DIST2(dA, dB)
    const float d0 = fmaxf(dA[0], 0.f);
    const float d1 = fmaxf(dA[1], 0.f);
    const float d2 = fmaxf(dB[0], 0.f);
    const float d3 = fmaxf(dB[1], 0.f);
    KNN_CHUNK(d0, dk0, ik0, T0, Th0);
    KNN_CHUNK(d1, dk1, ik1, T1, Th1);
    KNN_CHUNK(d2, dk2, ik2, T2, Th2);
    KNN_CHUNK(d3, dk3, ik3, T3, Th3);
  }

  if (lane < K_) {
    knn_idx[(size_t)(p0+0)*K_ + lane] = ik0;
    knn_idx[(size_t)(p0+1)*K_ + lane] = ik1;
    knn_idx[(size_t)(p0+2)*K_ + lane] = ik2;
    knn_idx[(size_t)(p0+3)*K_ + lane] = ik3;
  }
}

// ---------------- MFMA local_agg: transposed layout + 2-slot LDS dbuf + fused gmax ----------------
// r16: TWO k-slots staged per buffer -> 8 stages, 9 barriers (was 16/17).
// Same traffic, half the barrier-drain stalls at ~3 waves/SIMD occupancy.
template<int KS, int NPASS, bool GMAX>
__global__ __launch_bounds__(256) void aggm_kernel(
    const _Float16* __restrict__ fx, const int* __restrict__ knn_idx,
    const _Float16* __restrict__ midT, const _Float16* __restrict__ difT,
    const float* __restrict__ bw,
    _Float16* __restrict__ fo, const int ostr, u32* __restrict__ part) {
  const int XD  = KS*32;
  const int XDP = XD + 8;               // +16B pad per row
  const int CH  = KS*4;                 // uint4 chunks per row
  const int p0 = blockIdx.x * 16;
  const int bb = (p0 >> 13) << 13;
  const int tid = threadIdx.x;
  const int w = tid >> 6, lane = tid & 63, col = lane & 15, quad = lane >> 4;
  const int koff = quad * 8;

  __shared__ int s_idx[256];            // [point m][k]
  __shared__ _Float16 sA[2][32*(KS*32+8)];   // 2 bufs x 2 k-slots x 16 rows

  s_idx[tid] = knn_idx[p0*K_ + tid];

  // ---- C part (k-independent): A = own 16 point rows, B = difT ----
  f4v cacc[NPASS][2];
  {
    h8v Ao[KS];
    const _Float16* ap = fx + (size_t)(p0+col)*XD + koff;
#pragma unroll
    for (int kk = 0; kk < KS; ++kk) Ao[kk] = *(const h8v*)(ap + kk*32);
#pragma unroll
    for (int ps = 0; ps < NPASS; ++ps) {
      const int o0 = ps*128 + w*32;
      const _Float16* b0 = difT + (size_t)(o0 + col)*XD + koff;
      const _Float16* b1 = difT + (size_t)(o0 + 16 + col)*XD + koff;
      f4v c0 = {0.f,0.f,0.f,0.f}, c1 = {0.f,0.f,0.f,0.f};
#pragma unroll
      for (int kk = 0; kk < KS; ++kk) {
        c0 = MFMA16(Ao[kk], *(const h8v*)(b0 + kk*32), c0);
        c1 = MFMA16(Ao[kk], *(const h8v*)(b1 + kk*32), c1);
      }
      cacc[ps][0] = c0; cacc[ps][1] = c1;
    }
  }

  // ---- B fragments for ALL passes in registers ----
  h8v Bf[NPASS][2][KS];
  float bias[NPASS][2];
#pragma unroll
  for (int ps = 0; ps < NPASS; ++ps) {
    const int o0 = ps*128 + w*32;
#pragma unroll
    for (int kk = 0; kk < KS; ++kk) {
      Bf[ps][0][kk] = *(const h8v*)(midT + (size_t)(o0 + col)*XD + kk*32 + koff);
      Bf[ps][1][kk] = *(const h8v*)(midT + (size_t)(o0 + 16 + col)*XD + kk*32 + koff);
    }
    bias[ps][0] = bw[o0 + col];
    bias[ps][1] = bw[o0 + 16 + col];
  }
  __syncthreads();   // s_idx ready

  // ---- stage slots {0,1} ----  (sA row r: point r&15, slot offset r>>4)
  for (int c = tid; c < 32*CH; c += 256) {
    const int r = c / CH, o = c - r*CH;
    *(uint4*)&sA[0][r*XDP + o*8] =
        *(const uint4*)(fx + (size_t)(bb + s_idx[((r&15)<<4) + (r>>4)])*XD + o*8);
  }
  __syncthreads();

  f4v M[NPASS][2];
#pragma unroll
  for (int ps = 0; ps < NPASS; ++ps) {
    M[ps][0] = (f4v){-INFINITY,-INFINITY,-INFINITY,-INFINITY};
    M[ps][1] = (f4v){-INFINITY,-INFINITY,-INFINITY,-INFINITY};
  }

  for (int s = 0; s < 8; ++s) {
    const int buf = s & 1;
    if (s < 7) {   // stage slots {2s+2, 2s+3} into the other buffer
      for (int c = tid; c < 32*CH; c += 256) {
        const int r = c / CH, o = c - r*CH;
        *(uint4*)&sA[buf^1][r*XDP + o*8] =
            *(const uint4*)(fx + (size_t)(bb + s_idx[((r&15)<<4) + 2*s+2 + (r>>4)])*XD + o*8);
      }
    }
#pragma unroll
    for (int half = 0; half < 2; ++half) {
      h8v Ac[KS];
      const _Float16* ap = &sA[buf][(half*16 + col)*XDP + koff];
#pragma unroll
      for (int kk = 0; kk < KS; ++kk) Ac[kk] = *(const h8v*)(ap + kk*32);
#pragma unroll
      for (int ps = 0; ps < NPASS; ++ps) {
        f4v d0 = {0.f,0.f,0.f,0.f}, d1 = {0.f,0.f,0.f,0.f};
#pragma unroll
        for (int kk = 0; kk < KS; ++kk) {
          d0 = MFMA16(Ac[kk], Bf[ps][0][kk], d0);
          d1 = MFMA16(Ac[kk], Bf[ps][1][kk], d1);
        }
#pragma unroll
        for (int e = 0; e < 4; ++e) {
          M[ps][0][e] = fmaxf(M[ps][0][e], d0[e]);
          M[ps][1][e] = fmaxf(M[ps][1][e], d1[e]);
        }
      }
    }
    __syncthreads();   // staged data visible; readers done before overwrite
  }

  // ---- epilogue: out[p][o] = max(M + C + bias, 0); lane holds rows quad*4+reg ----
  const int prow = p0 + (quad << 2);
  const int bq = p0 >> 13;
#pragma unroll
  for (int ps = 0; ps < NPASS; ++ps) {
    const int o0 = ps*128 + w*32;
    const int oa = o0 + col, ob = oa + 16;
    float v0[4], v1[4];
#pragma unroll
    for (int reg = 0; reg < 4; ++reg) {
      v0[reg] = fmaxf(M[ps][0][reg] + cacc[ps][0][reg] + bias[ps][0], 0.f);
      v1[reg] = fmaxf(M[ps][1][reg] + cacc[ps][1][reg] + bias[ps][1], 0.f);
      fo[(size_t)(prow+reg)*ostr + oa] = (_Float16)v0[reg];
      fo[(size_t)(prow+reg)*ostr + ob] = (_Float16)v1[reg];
    }
    if (GMAX) {   // block-local max over 16 points, then one atomic per output
      float bm0 = fmaxf(fmaxf(v0[0], v0[1]), fmaxf(v0[2], v0[3]));
      float bm1 = fmaxf(fmaxf(v1[0], v1[1]), fmaxf(v1[2], v1[3]));
      bm0 = fmaxf(bm0, __shfl_xor(bm0, 16, 64));
      bm0 = fmaxf(bm0, __shfl_xor(bm0, 32, 64));
      bm1 = fmaxf(bm1, __shfl_xor(bm1, 16, 64));
      bm1 = fmaxf(bm1, __shfl_xor(bm1, 32, 64));
      if (quad == 0) {
        atomicMax(part + bq*W2_ + oa, __float_as_uint(bm0));
        atomicMax(part + bq*W2_ + ob, __float_as_uint(bm1));
      }
    }
  }
}

// ---------------- glob FC from fused-max part -> g2h fp16 (r14 version) ----------------
__global__ __launch_bounds__(256) void gfc_kernel(
    const float* __restrict__ part, const float* __restrict__ gw,
    const float* __restrict__ gb, _Float16* __restrict__ g2h) {
  const int b = blockIdx.x;
  const int o = threadIdx.x;
  __shared__ float s_g[W2_];
  s_g[o] = part[b*W2_ + o];   // bits from atomicMax(u32) == float bits (>=0)
  __syncthreads();
  float acc = gb[o];
  for (int d = 0; d < W2_; ++d) acc += s_g[d]*gw[d*W2_ + o];
  g2h[b*W2_ + o] = (_Float16)fmaxf(acc, 0.f);
}

// ---------------- head: 32 points/block MFMA GEMM + tiny second layer (r14 version) ----------------
__global__ __launch_bounds__(256) void headm_kernel(
    const _Float16* __restrict__ f2h, const _Float16* __restrict__ g2h,
    const _Float16* __restrict__ h1wT, const float* __restrict__ h1b,
    const float* __restrict__ h2w, const float* __restrict__ h2b,
    const float* __restrict__ x,
    const float* __restrict__ thresh, const float* __restrict__ sharp,
    const float* __restrict__ scale,
    float* __restrict__ out) {
  const int p0 = blockIdx.x * 32;
  const int b = p0 >> 13;
  const int tid = threadIdx.x;
  const int w = tid >> 6, lane = tid & 63, col = lane & 15, quad = lane >> 4;

  __shared__ _Float16 sA[32*520];   // 32 points x 512 (padded to 520)
  __shared__ float    sh[32*260];   // relu(h1) f32

  for (int t = tid; t < 32*32; t += 256) {       // f2h part (16B chunks)
    const int r = t >> 5, cc = (t & 31) * 8;
    *(uint4*)&sA[r*520 + cc] = *(const uint4*)&f2h[(size_t)(p0+r)*W2_ + cc];
  }
  for (int t = tid; t < 32*32; t += 256) {       // g2h broadcast part
    const int r = t >> 5, cc = (t & 31) * 8;
    *(uint4*)&sA[r*520 + 256 + cc] = *(const uint4*)&g2h[b*W2_ + cc];
  }
  __syncthreads();

  f4v acc[2][4];
#pragma unroll
  for (int r = 0; r < 2; ++r)
#pragma unroll
    for (int t = 0; t < 4; ++t) acc[r][t] = (f4v){0.f,0.f,0.f,0.f};

  for (int kk = 0; kk < 16; ++kk) {
    const h8v a0 = *(const h8v*)&sA[col*520 + kk*32 + quad*8];
    const h8v a1 = *(const h8v*)&sA[(16+col)*520 + kk*32 + quad*8];
#pragma unroll
    for (int t = 0; t < 4; ++t) {
      const h8v bt = *(const h8v*)&h1wT[(size_t)(w*64 + t*16 + col)*512 + kk*32 + quad*8];
      acc[0][t] = MFMA16(a0, bt, acc[0][t]);
      acc[1][t] = MFMA16(a1, bt, acc[1][t]);
    }
  }
#pragma unroll
  for (int r = 0; r < 2; ++r)
#pragma unroll
    for (int t = 0; t < 4; ++t) {
      const int o = w*64 + t*16 + col;
      const float bv = h1b[o];
#pragma unroll
      for (int reg = 0; reg < 4; ++reg)
        sh[(r*16 + quad*4 + reg)*260 + o] = fmaxf(acc[r][t][reg] + bv, 0.f);
    }
  __syncthreads();

  if (tid < 96) {
    const int pp = tid / 3, c = tid % 3;
    float s = h2b[c];
    for (int d = 0; d < 256; ++d) s += sh[pp*260 + d] * h2w[d*3 + c];
    if (c == 0) {
      const float hag = x[(size_t)(p0+pp)*4 + 3];
      s += scale[0] / (1.f + expf(-sharp[0]*(thresh[0] - hag)));
    }
    out[(size_t)(p0+pp)*3 + c] = s;
  }
}

// ---------------- launch ----------------
extern "C" void kernel_launch(void* const* d_in, const int* in_sizes, int n_in,
                              void* d_out, int out_size, void* d_ws, size_t ws_size,
                              hipStream_t stream) {
  const float* x       = (const float*)d_in[0];
  const float* hmix_a  = (const float*)d_in[1];
  const float* hmix_b  = (const float*)d_in[2];
  const float* hmix_c  = (const float*)d_in[3];
  const float* stem_w  = (const float*)d_in[4];
  const float* stem_b  = (const float*)d_in[5];
  const float* b1_w    = (const float*)d_in[6];
  const float* b1_b    = (const float*)d_in[7];
  const float* b2_w    = (const float*)d_in[8];
  const float* b2_b    = (const float*)d_in[9];
  const float* glob_w  = (const float*)d_in[10];
  const float* glob_b  = (const float*)d_in[11];
  const float* head1_w = (const float*)d_in[12];
  const float* head1_b = (const float*)d_in[13];
  const float* head2_w = (const float*)d_in[14];
  const float* head2_b = (const float*)d_in[15];
  const float* thresh  = (const float*)d_in[16];
  const float* sharp   = (const float*)d_in[17];
  const float* scale   = (const float*)d_in[18];
  float* out = (float*)d_out;

  char* base = (char*)d_ws;
  float*     coords4 = (float*)    (base + 0);          // 512 KB
  int*       idxb    = (int*)      (base + 524288);     // 2 MB
  _Float16*  fx0     = (_Float16*) (base + 2621440);    // 6 MB   (32768*96*2)
  _Float16*  fx1     = (_Float16*) (base + 8912896);    // 10 MB  (32768*160*2)
  _Float16*  f2h     = (_Float16*) (base + 19398656);   // 16 MB  (32768*256*2)
  _Float16*  w1m     = (_Float16*) (base + 36175872);   // 24 KB  (128*96*2)
  _Float16*  w1d     = (_Float16*) (base + 36200448);   // 24 KB
  _Float16*  w2m     = (_Float16*) (base + 36225024);   // 80 KB  (256*160*2)
  _Float16*  w2d     = (_Float16*) (base + 36306944);   // 80 KB
  _Float16*  h1wT    = (_Float16*) (base + 36388864);   // 256 KB (256*512*2)
  float*     part    = (float*)    (base + 36651008);   // 4 KB (4*256 f32, fused max)
  _Float16*  g2h     = (_Float16*) (base + 36782080);   // 2 KB
  const int NP = B_ * N_;   // 32768 points

  prep_kernel<<<NP/4 + W1_ + 2*W2_ + 1, 256, 0, stream>>>(
      x, stem_w, stem_b, hmix_a, hmix_b, hmix_c, coords4, fx0, fx1,
      b1_w, b2_w, head1_w, w1m, w1d, w2m, w2d, h1wT, part);
  knn_kernel<<<NP/16, 256, 0, stream>>>(coords4, idxb);
  aggm_kernel<3, 1, false><<<NP/16, 256, 0, stream>>>(
      fx0, idxb, w1m, w1d, b1_b, fx1, X1_, (u32*)0);
  aggm_kernel<5, 2, true><<<NP/16, 256, 0, stream>>>(
      fx1, idxb, w2m, w2d, b2_b, f2h, W2_, (u32*)part);
  gfc_kernel<<<B_, 256, 0, stream>>>(part, glob_w, glob_b, g2h);
  headm_kernel<<<NP/32, 256, 0, stream>>>(f2h, g2h, h1wT, head1_b, head2_w, head2_b,
                                          x, thresh, sharp, scale, out);
}

// Round 17
// 411.486 us; speedup vs baseline: 1.1120x; 1.0038x over previous
//
#include <hip/hip_runtime.h>
#include <math.h>

typedef unsigned long long u64;
typedef unsigned int u32;
typedef _Float16 h8v __attribute__((ext_vector_type(8)));  // 8 fp16 (4 VGPRs)
typedef float    f4v __attribute__((ext_vector_type(4)));  // MFMA acc
typedef float    f2v __attribute__((ext_vector_type(2)));  // v_pk_*_f32 pair

#define MFMA16(a,b,c) __builtin_amdgcn_mfma_f32_16x16x32_f16(a, b, c, 0, 0, 0)

#define B_ 4
#define N_ 8192
#define K_ 16
#define W0_ 64
#define W1_ 128
#define W2_ 256
#define X0_ 96   // padded K-dim layer-1 inputs (64 feat + 3 coord + 29 zero)
#define X1_ 160  // padded K-dim layer-2 inputs (128 feat + 3 coord + 29 zero)

// ---------------- merged prep: points + weight conversions + part zeroing ----------------
__global__ __launch_bounds__(256) void prep_kernel(
    const float* __restrict__ x,
    const float* __restrict__ stem_w, const float* __restrict__ stem_b,
    const float* __restrict__ hmix_a, const float* __restrict__ hmix_b,
    const float* __restrict__ hmix_c,
    float* __restrict__ coords4, _Float16* __restrict__ fx0,
    _Float16* __restrict__ fx1,
    const float* __restrict__ b1_w, const float* __restrict__ b2_w,
    const float* __restrict__ h1w,
    _Float16* __restrict__ w1m, _Float16* __restrict__ w1d,
    _Float16* __restrict__ w2m, _Float16* __restrict__ w2d,
    _Float16* __restrict__ h1wT, float* __restrict__ part) {
  const int bi = blockIdx.x;
  const int tid = threadIdx.x;
  const int PB = (B_*N_)/4;          // 8192
  if (bi < PB) {
    const int p = bi * 4 + (tid >> 6);
    const int o = tid & 63;
    const float x0 = x[p*4+0], x1 = x[p*4+1], x2 = x[p*4+2], x3 = x[p*4+3];
    const float z = hmix_a[0]*x2 + hmix_b[0]*x3 + hmix_c[0];
    float acc = stem_b[o] + x0*stem_w[0*W0_+o] + x1*stem_w[1*W0_+o]
              + x2*stem_w[2*W0_+o] + x3*stem_w[3*W0_+o];
    fx0[p*X0_+o] = (_Float16)fmaxf(acc, 0.f);
    if (o < 32) {   // tail: 3 coords + 29 zeros (both layers' inputs)
      const float tv = (o==0) ? x0 : (o==1) ? x1 : (o==2) ? z : 0.f;
      fx0[p*X0_+W0_+o] = (_Float16)tv;
      fx1[(size_t)p*X1_+W1_+o] = (_Float16)tv;
    }
    if (o == 0) {
      const float xx = x0*x0 + x1*x1 + z*z;
      ((float4*)coords4)[p] = make_float4(x0, x1, z, xx);
    }
  } else if (bi < PB + W1_) {        // wconv layer1
    const int o = bi - PB, c = tid;
    if (c < X0_) {
      float mv = 0.f, dv = 0.f;
      if (c < W0_)        { const float wm = b1_w[(W0_+c)*W1_+o]; mv = wm; dv = b1_w[c*W1_+o] - wm; }
      else if (c < W0_+3) { const float wp = b1_w[(2*W0_+(c-W0_))*W1_+o]; mv = wp; dv = -wp; }
      w1m[o*X0_+c] = (_Float16)mv;
      w1d[o*X0_+c] = (_Float16)dv;
    }
  } else if (bi < PB + W1_ + W2_) {  // wconv layer2
    const int o = bi - PB - W1_, c = tid;
    if (c < X1_) {
      float mv = 0.f, dv = 0.f;
      if (c < W1_)        { const float wm = b2_w[(W1_+c)*W2_+o]; mv = wm; dv = b2_w[c*W2_+o] - wm; }
      else if (c < W1_+3) { const float wp = b2_w[(2*W1_+(c-W1_))*W2_+o]; mv = wp; dv = -wp; }
      w2m[o*X1_+c] = (_Float16)mv;
      w2d[o*X1_+c] = (_Float16)dv;
    }
  } else if (bi < PB + W1_ + 2*W2_) { // head1 transpose
    const int o = bi - PB - W1_ - W2_;
    for (int c = tid; c < 512; c += 256)
      h1wT[(size_t)o*512 + c] = (_Float16)h1w[(size_t)c*256 + o];
  } else {                            // zero part (B_*W2_ = 1024 floats)
    ((float4*)part)[tid] = make_float4(0.f, 0.f, 0.f, 0.f);
  }
}

// ---------------- knn: 4 waves x 4 points, packed-f32 distances, threshold pre-pass ----------------
// Selection exact (r9 bound proof; quarter-sample T-hat is still a valid upper
// bound). Structure frozen since r16 — at its issue-bound floor (r15 refuted
// wider per-wave batching, r10 refuted occupancy, r8 refuted latency).
#define DPP_SHR1(v) __builtin_amdgcn_update_dpp(0, (v), 0x138, 0xF, 0xF, false)

#define DPP_MIN(v, ctrl)                                                        \
  { const int _t = __builtin_amdgcn_update_dpp(__float_as_int(v),               \
      __float_as_int(v), ctrl, 0xF, 0xF, false);                                \
    v = fminf(v, __int_as_float(_t)); }

__device__ __forceinline__ float sixteenth_of_minima(float v) {
  float th = 0.f;
#pragma unroll
  for (int r = 0; r < 16; ++r) {
    float w = v;
    DPP_MIN(w, 0x111); DPP_MIN(w, 0x112); DPP_MIN(w, 0x114); DPP_MIN(w, 0x118);
    DPP_MIN(w, 0x142); DPP_MIN(w, 0x143);   // row_bcast15 / row_bcast31
    const float mv = __int_as_float(
        __builtin_amdgcn_readlane(__float_as_int(w), 63));
    th = mv;
    v = (v == mv) ? INFINITY : v;
  }
  return th;
}

#define KNN_EVT(d, dk, ik)                                                      \
  {                                                                             \
    const int s = (int)__ffsll((unsigned long long)m) - 1;  m &= m - 1;         \
    const float dc = __int_as_float(__builtin_amdgcn_readlane(                  \
                       __float_as_int(d), s));                                  \
    const bool cnd = dc < dk;                                                   \
    const u64 cm = __ballot(cnd) << 1;                                          \
    const float pd = __int_as_float(DPP_SHR1(__float_as_int(dk)));              \
    const int   pi = DPP_SHR1(ik);                                              \
    const bool pc = (cm >> lane) & 1;                                           \
    dk = cnd ? (pc ? pd : dc) : dk;                                             \
    ik = cnd ? (pc ? pi : (jbase + s)) : ik;                                    \
  }

#define KNN_CHUNK(d, dk, ik, T, Th)                                             \
  { u64 m = __ballot(d <= T);                                                   \
    if (m) {                                                                    \
      do { KNN_EVT(d, dk, ik) } while (m);                                      \
      T = fminf(Th, __int_as_float(__builtin_amdgcn_readlane(                   \
            __float_as_int(dk), 15)));                                          \
    }                                                                           \
  }

#define KNN_DIST2(dA, dB)                                                       \
  const f2v cjx = {cj.x, cj.x}, cjy = {cj.y, cj.y},                             \
            cjz = {cj.z, cj.z}, cjw = {cj.w, cj.w};                             \
  f2v tA = cAx * cjx;                                                           \
  tA = __builtin_elementwise_fma(cAy, cjy, tA);                                 \
  tA = __builtin_elementwise_fma(cAz, cjz, tA);                                 \
  const f2v dA = __builtin_elementwise_fma(tA, m2, cAw + cjw);                  \
  f2v tB = cBx * cjx;                                                           \
  tB = __builtin_elementwise_fma(cBy, cjy, tB);                                 \
  tB = __builtin_elementwise_fma(cBz, cjz, tB);                                 \
  const f2v dB = __builtin_elementwise_fma(tB, m2, cBw + cjw);

__global__ __launch_bounds__(256, 8) void knn_kernel(
    const float* __restrict__ coords4, int* __restrict__ knn_idx) {
  const int tid = threadIdx.x;
  const int wid = tid >> 6;
  const int lane = tid & 63;
  const int p0 = blockIdx.x * 16 + wid * 4;   // block of 16 never straddles batch
  const int b = p0 >> 13;
  const float4* cb = ((const float4*)coords4) + (b << 13);
  const float4 c0 = ((const float4*)coords4)[p0+0];
  const float4 c1 = ((const float4*)coords4)[p0+1];
  const float4 c2 = ((const float4*)coords4)[p0+2];
  const float4 c3 = ((const float4*)coords4)[p0+3];
  const f2v m2 = {-2.f, -2.f};
  const f2v cAx = {c0.x, c1.x}, cAy = {c0.y, c1.y}, cAz = {c0.z, c1.z}, cAw = {c0.w, c1.w};
  const f2v cBx = {c2.x, c3.x}, cBy = {c2.y, c3.y}, cBz = {c2.z, c3.z}, cBw = {c2.w, c3.w};

  // ---- pass A: per-lane minima over a quarter sample (straight-line, no events)
  float lm0 = INFINITY, lm1 = INFINITY, lm2 = INFINITY, lm3 = INFINITY;
  for (int it = 0; it < 32; ++it) {
    const float4 cj = cb[it*64 + lane];
    KNN_DIST2(dA, dB)
    lm0 = fminf(lm0, fmaxf(dA[0], 0.f));
    lm1 = fminf(lm1, fmaxf(dA[1], 0.f));
    lm2 = fminf(lm2, fmaxf(dB[0], 0.f));
    lm3 = fminf(lm3, fmaxf(dB[1], 0.f));
  }
  const float Th0 = sixteenth_of_minima(lm0);
  const float Th1 = sixteenth_of_minima(lm1);
  const float Th2 = sixteenth_of_minima(lm2);
  const float Th3 = sixteenth_of_minima(lm3);

  float dk0 = INFINITY, dk1 = INFINITY, dk2 = INFINITY, dk3 = INFINITY;
  int   ik0 = 0, ik1 = 0, ik2 = 0, ik3 = 0;
  float T0 = Th0, T1 = Th1, T2 = Th2, T3 = Th3;

  // ---- main pass: all candidates, events only below the bound
  for (int it = 0; it < N_/64; ++it) {
    const int jbase = it*64;
    const float4 cj = cb[jbase + lane];
    KNN_DIST2(dA, dB)
    const float d0 = fmaxf(dA[0], 0.f);
    const float d1 = fmaxf(dA[1], 0.f);
    const float d2 = fmaxf(dB[0], 0.f);
    const float d3 = fmaxf(dB[1], 0.f);
    KNN_CHUNK(d0, dk0, ik0, T0, Th0);
    KNN_CHUNK(d1, dk1, ik1, T1, Th1);
    KNN_CHUNK(d2, dk2, ik2, T2, Th2);
    KNN_CHUNK(d3, dk3, ik3, T3, Th3);
  }

  if (lane < K_) {
    knn_idx[(size_t)(p0+0)*K_ + lane] = ik0;
    knn_idx[(size_t)(p0+1)*K_ + lane] = ik1;
    knn_idx[(size_t)(p0+2)*K_ + lane] = ik2;
    knn_idx[(size_t)(p0+3)*K_ + lane] = ik3;
  }
}

// ---------------- MFMA local_agg: transposed layout + 4-slot LDS dbuf + fused gmax ----------------
// r17: FOUR k-slots staged per buffer -> 4 stages, 5 barriers total (was 9).
// Same traffic & arithmetic; occupancy unchanged (VGPR-bound at ~3 waves/SIMD,
// LDS 43KB still allows 3 blocks/CU). Pure barrier-drain reduction (r16 priced
// a barrier at ~2us/dispatch at this occupancy).
template<int KS, int NPASS, bool GMAX>
__global__ __launch_bounds__(256) void aggm_kernel(
    const _Float16* __restrict__ fx, const int* __restrict__ knn_idx,
    const _Float16* __restrict__ midT, const _Float16* __restrict__ difT,
    const float* __restrict__ bw,
    _Float16* __restrict__ fo, const int ostr, u32* __restrict__ part) {
  const int XD  = KS*32;
  const int XDP = XD + 8;               // +16B pad per row
  const int CH  = KS*4;                 // uint4 chunks per row
  const int p0 = blockIdx.x * 16;
  const int bb = (p0 >> 13) << 13;
  const int tid = threadIdx.x;
  const int w = tid >> 6, lane = tid & 63, col = lane & 15, quad = lane >> 4;
  const int koff = quad * 8;

  __shared__ int s_idx[256];            // [point m][k]
  __shared__ _Float16 sA[2][64*(KS*32+8)];   // 2 bufs x 4 k-slots x 16 rows

  s_idx[tid] = knn_idx[p0*K_ + tid];

  // ---- C part (k-independent): A = own 16 point rows, B = difT ----
  f4v cacc[NPASS][2];
  {
    h8v Ao[KS];
    const _Float16* ap = fx + (size_t)(p0+col)*XD + koff;
#pragma unroll
    for (int kk = 0; kk < KS; ++kk) Ao[kk] = *(const h8v*)(ap + kk*32);
#pragma unroll
    for (int ps = 0; ps < NPASS; ++ps) {
      const int o0 = ps*128 + w*32;
      const _Float16* b0 = difT + (size_t)(o0 + col)*XD + koff;
      const _Float16* b1 = difT + (size_t)(o0 + 16 + col)*XD + koff;
      f4v c0 = {0.f,0.f,0.f,0.f}, c1 = {0.f,0.f,0.f,0.f};
#pragma unroll
      for (int kk = 0; kk < KS; ++kk) {
        c0 = MFMA16(Ao[kk], *(const h8v*)(b0 + kk*32), c0);
        c1 = MFMA16(Ao[kk], *(const h8v*)(b1 + kk*32), c1);
      }
      cacc[ps][0] = c0; cacc[ps][1] = c1;
    }
  }

  // ---- B fragments for ALL passes in registers ----
  h8v Bf[NPASS][2][KS];
  float bias[NPASS][2];
#pragma unroll
  for (int ps = 0; ps < NPASS; ++ps) {
    const int o0 = ps*128 + w*32;
#pragma unroll
    for (int kk = 0; kk < KS; ++kk) {
      Bf[ps][0][kk] = *(const h8v*)(midT + (size_t)(o0 + col)*XD + kk*32 + koff);
      Bf[ps][1][kk] = *(const h8v*)(midT + (size_t)(o0 + 16 + col)*XD + kk*32 + koff);
    }
    bias[ps][0] = bw[o0 + col];
    bias[ps][1] = bw[o0 + 16 + col];
  }
  __syncthreads();   // s_idx ready

  // ---- stage slots {0..3} ----  (sA row r: point r&15, slot base + (r>>4))
  for (int c = tid; c < 64*CH; c += 256) {
    const int r = c / CH, o = c - r*CH;
    *(uint4*)&sA[0][r*XDP + o*8] =
        *(const uint4*)(fx + (size_t)(bb + s_idx[((r&15)<<4) + (r>>4)])*XD + o*8);
  }
  __syncthreads();

  f4v M[NPASS][2];
#pragma unroll
  for (int ps = 0; ps < NPASS; ++ps) {
    M[ps][0] = (f4v){-INFINITY,-INFINITY,-INFINITY,-INFINITY};
    M[ps][1] = (f4v){-INFINITY,-INFINITY,-INFINITY,-INFINITY};
  }

  for (int s = 0; s < 4; ++s) {
    const int buf = s & 1;
    if (s < 3) {   // stage slots {4s+4 .. 4s+7} into the other buffer
      for (int c = tid; c < 64*CH; c += 256) {
        const int r = c / CH, o = c - r*CH;
        *(uint4*)&sA[buf^1][r*XDP + o*8] =
            *(const uint4*)(fx + (size_t)(bb + s_idx[((r&15)<<4) + 4*s+4 + (r>>4)])*XD + o*8);
      }
    }
#pragma unroll
    for (int half = 0; half < 4; ++half) {
      h8v Ac[KS];
      const _Float16* ap = &sA[buf][(half*16 + col)*XDP + koff];
#pragma unroll
      for (int kk = 0; kk < KS; ++kk) Ac[kk] = *(const h8v*)(ap + kk*32);
#pragma unroll
      for (int ps = 0; ps < NPASS; ++ps) {
        f4v d0 = {0.f,0.f,0.f,0.f}, d1 = {0.f,0.f,0.f,0.f};
#pragma unroll
        for (int kk = 0; kk < KS; ++kk) {
          d0 = MFMA16(Ac[kk], Bf[ps][0][kk], d0);
          d1 = MFMA16(Ac[kk], Bf[ps][1][kk], d1);
        }
#pragma unroll
        for (int e = 0; e < 4; ++e) {
          M[ps][0][e] = fmaxf(M[ps][0][e], d0[e]);
          M[ps][1][e] = fmaxf(M[ps][1][e], d1[e]);
        }
      }
    }
    if (s < 3) __syncthreads();   // staged visible; readers done before overwrite
  }

  // ---- epilogue: out[p][o] = max(M + C + bias, 0); lane holds rows quad*4+reg ----
  const int prow = p0 + (quad << 2);
  const int bq = p0 >> 13;
#pragma unroll
  for (int ps = 0; ps < NPASS; ++ps) {
    const int o0 = ps*128 + w*32;
    const int oa = o0 + col, ob = oa + 16;
    float v0[4], v1[4];
#pragma unroll
    for (int reg = 0; reg < 4; ++reg) {
      v0[reg] = fmaxf(M[ps][0][reg] + cacc[ps][0][reg] + bias[ps][0], 0.f);
      v1[reg] = fmaxf(M[ps][1][reg] + cacc[ps][1][reg] + bias[ps][1], 0.f);
      fo[(size_t)(prow+reg)*ostr + oa] = (_Float16)v0[reg];
      fo[(size_t)(prow+reg)*ostr + ob] = (_Float16)v1[reg];
    }
    if (GMAX) {   // block-local max over 16 points, then one atomic per output
      float bm0 = fmaxf(fmaxf(v0[0], v0[1]), fmaxf(v0[2], v0[3]));
      float bm1 = fmaxf(fmaxf(v1[0], v1[1]), fmaxf(v1[2], v1[3]));
      bm0 = fmaxf(bm0, __shfl_xor(bm0, 16, 64));
      bm0 = fmaxf(bm0, __shfl_xor(bm0, 32, 64));
      bm1 = fmaxf(bm1, __shfl_xor(bm1, 16, 64));
      bm1 = fmaxf(bm1, __shfl_xor(bm1, 32, 64));
      if (quad == 0) {
        atomicMax(part + bq*W2_ + oa, __float_as_uint(bm0));
        atomicMax(part + bq*W2_ + ob, __float_as_uint(bm1));
      }
    }
  }
}

// ---------------- glob FC from fused-max part -> g2h fp16 ----------------
__global__ __launch_bounds__(256) void gfc_kernel(
    const float* __restrict__ part, const float* __restrict__ gw,
    const float* __restrict__ gb, _Float16* __restrict__ g2h) {
  const int b = blockIdx.x;
  const int o = threadIdx.x;
  __shared__ float s_g[W2_];
  s_g[o] = part[b*W2_ + o];   // bits from atomicMax(u32) == float bits (>=0)
  __syncthreads();
  float acc = gb[o];
  for (int d = 0; d < W2_; ++d) acc += s_g[d]*gw[d*W2_ + o];
  g2h[b*W2_ + o] = (_Float16)fmaxf(acc, 0.f);
}

// ---------------- head: 32 points/block MFMA GEMM + tiny second layer ----------------
__global__ __launch_bounds__(256) void headm_kernel(
    const _Float16* __restrict__ f2h, const _Float16* __restrict__ g2h,
    const _Float16* __restrict__ h1wT, const float* __restrict__ h1b,
    const float* __restrict__ h2w, const float* __restrict__ h2b,
    const float* __restrict__ x,
    const float* __restrict__ thresh, const float* __restrict__ sharp,
    const float* __restrict__ scale,
    float* __restrict__ out) {
  const int p0 = blockIdx.x * 32;
  const int b = p0 >> 13;
  const int tid = threadIdx.x;
  const int w = tid >> 6, lane = tid & 63, col = lane & 15, quad = lane >> 4;

  __shared__ _Float16 sA[32*520];   // 32 points x 512 (padded to 520)
  __shared__ float    sh[32*260];   // relu(h1) f32

  for (int t = tid; t < 32*32; t += 256) {       // f2h part (16B chunks)
    const int r = t >> 5, cc = (t & 31) * 8;
    *(uint4*)&sA[r*520 + cc] = *(const uint4*)&f2h[(size_t)(p0+r)*W2_ + cc];
  }
  for (int t = tid; t < 32*32; t += 256) {       // g2h broadcast part
    const int r = t >> 5, cc = (t & 31) * 8;
    *(uint4*)&sA[r*520 + 256 + cc] = *(const uint4*)&g2h[b*W2_ + cc];
  }
  __syncthreads();

  f4v acc[2][4];
#pragma unroll
  for (int r = 0; r < 2; ++r)
#pragma unroll
    for (int t = 0; t < 4; ++t) acc[r][t] = (f4v){0.f,0.f,0.f,0.f};

  for (int kk = 0; kk < 16; ++kk) {
    const h8v a0 = *(const h8v*)&sA[col*520 + kk*32 + quad*8];
    const h8v a1 = *(const h8v*)&sA[(16+col)*520 + kk*32 + quad*8];
#pragma unroll
    for (int t = 0; t < 4; ++t) {
      const h8v bt = *(const h8v*)&h1wT[(size_t)(w*64 + t*16 + col)*512 + kk*32 + quad*8];
      acc[0][t] = MFMA16(a0, bt, acc[0][t]);
      acc[1][t] = MFMA16(a1, bt, acc[1][t]);
    }
  }
#pragma unroll
  for (int r = 0; r < 2; ++r)
#pragma unroll
    for (int t = 0; t < 4; ++t) {
      const int o = w*64 + t*16 + col;
      const float bv = h1b[o];
#pragma unroll
      for (int reg = 0; reg < 4; ++reg)
        sh[(r*16 + quad*4 + reg)*260 + o] = fmaxf(acc[r][t][reg] + bv, 0.f);
    }
  __syncthreads();

  if (tid < 96) {
    const int pp = tid / 3, c = tid % 3;
    float s = h2b[c];
    for (int d = 0; d < 256; ++d) s += sh[pp*260 + d] * h2w[d*3 + c];
    if (c == 0) {
      const float hag = x[(size_t)(p0+pp)*4 + 3];
      s += scale[0] / (1.f + expf(-sharp[0]*(thresh[0] - hag)));
    }
    out[(size_t)(p0+pp)*3 + c] = s;
  }
}

// ---------------- launch ----------------
extern "C" void kernel_launch(void* const* d_in, const int* in_sizes, int n_in,
                              void* d_out, int out_size, void* d_ws, size_t ws_size,
                              hipStream_t stream) {
  const float* x       = (const float*)d_in[0];
  const float* hmix_a  = (const float*)d_in[1];
  const float* hmix_b  = (const float*)d_in[2];
  const float* hmix_c  = (const float*)d_in[3];
  const float* stem_w  = (const float*)d_in[4];
  const float* stem_b  = (const float*)d_in[5];
  const float* b1_w    = (const float*)d_in[6];
  const float* b1_b    = (const float*)d_in[7];
  const float* b2_w    = (const float*)d_in[8];
  const float* b2_b    = (const float*)d_in[9];
  const float* glob_w  = (const float*)d_in[10];
  const float* glob_b  = (const float*)d_in[11];
  const float* head1_w = (const float*)d_in[12];
  const float* head1_b = (const float*)d_in[13];
  const float* head2_w = (const float*)d_in[14];
  const float* head2_b = (const float*)d_in[15];
  const float* thresh  = (const float*)d_in[16];
  const float* sharp   = (const float*)d_in[17];
  const float* scale   = (const float*)d_in[18];
  float* out = (float*)d_out;

  char* base = (char*)d_ws;
  float*     coords4 = (float*)    (base + 0);          // 512 KB
  int*       idxb    = (int*)      (base + 524288);     // 2 MB
  _Float16*  fx0     = (_Float16*) (base + 2621440);    // 6 MB   (32768*96*2)
  _Float16*  fx1     = (_Float16*) (base + 8912896);    // 10 MB  (32768*160*2)
  _Float16*  f2h     = (_Float16*) (base + 19398656);   // 16 MB  (32768*256*2)
  _Float16*  w1m     = (_Float16*) (base + 36175872);   // 24 KB  (128*96*2)
  _Float16*  w1d     = (_Float16*) (base + 36200448);   // 24 KB
  _Float16*  w2m     = (_Float16*) (base + 36225024);   // 80 KB  (256*160*2)
  _Float16*  w2d     = (_Float16*) (base + 36306944);   // 80 KB
  _Float16*  h1wT    = (_Float16*) (base + 36388864);   // 256 KB (256*512*2)
  float*     part    = (float*)    (base + 36651008);   // 4 KB (4*256 f32, fused max)
  _Float16*  g2h     = (_Float16*) (base + 36782080);   // 2 KB
  const int NP = B_ * N_;   // 32768 points

  prep_kernel<<<NP/4 + W1_ + 2*W2_ + 1, 256, 0, stream>>>(
      x, stem_w, stem_b, hmix_a, hmix_b, hmix_c, coords4, fx0, fx1,
      b1_w, b2_w, head1_w, w1m, w1d, w2m, w2d, h1wT, part);
  knn_kernel<<<NP/16, 256, 0, stream>>>(coords4, idxb);
  aggm_kernel<3, 1, false><<<NP/16, 256, 0, stream>>>(
      fx0, idxb, w1m, w1d, b1_b, fx1, X1_, (u32*)0);
  aggm_kernel<5, 2, true><<<NP/16, 256, 0, stream>>>(
      fx1, idxb, w2m, w2d, b2_b, f2h, W2_, (u32*)part);
  gfc_kernel<<<B_, 256, 0, stream>>>(part, glob_w, glob_b, g2h);
  headm_kernel<<<NP/32, 256, 0, stream>>>(f2h, g2h, h1wT, head1_b, head2_w, head2_b,
                                          x, thresh, sharp, scale, out);
}